// Round 1
// baseline (352.582 us; speedup 1.0000x reference)
//
#include <hip/hip_runtime.h>

// GaussianLikelihoodLoss: mean over (b,t) of d^T Sigma^{-1} d + log|Sigma|
// pred/target: [B,N,T] f32 ; cov: [B,N,N,T] f32 ; out: scalar f32
// B=1024, N=16, T=256. Per (b,t): 16x16 Cholesky in registers.

#define B_ 1024
#define N_ 16
#define T_ 256
#define TRI (N_ * (N_ + 1) / 2)   // 136

__global__ __launch_bounds__(256) void gll_main(
    const float* __restrict__ pred,
    const float* __restrict__ targ,
    const float* __restrict__ cov,
    float* __restrict__ partial)
{
    const int b = blockIdx.x;      // one block per batch
    const int t = threadIdx.x;     // one thread per time step

    // diff vector, coalesced across t
    float d[N_];
    const size_t pbase = (size_t)b * N_ * T_ + t;
#pragma unroll
    for (int n = 0; n < N_; ++n)
        d[n] = pred[pbase + n * T_] - targ[pbase + n * T_];

    // lower triangle of cov[b,i,j,t]; each (i,j) is a contiguous 1KB row over t
    float L[TRI];
    const size_t cbase = (size_t)b * N_ * N_ * T_ + t;
#pragma unroll
    for (int i = 0; i < N_; ++i)
#pragma unroll
        for (int j = 0; j <= i; ++j)
            L[i * (i + 1) / 2 + j] = cov[cbase + (size_t)(i * N_ + j) * T_];

    // In-place Cholesky. Diagonal slots store 1/L_ii (rsqrt of pivot).
    // logdet = sum log(pivot_i)  (== 2*sum log L_ii)
    float logdet = 0.f;
#pragma unroll
    for (int i = 0; i < N_; ++i) {
#pragma unroll
        for (int j = 0; j < i; ++j) {
            float s = L[i * (i + 1) / 2 + j];
#pragma unroll
            for (int k = 0; k < j; ++k)
                s -= L[i * (i + 1) / 2 + k] * L[j * (j + 1) / 2 + k];
            L[i * (i + 1) / 2 + j] = s * L[j * (j + 1) / 2 + j]; // * invL_jj
        }
        float s = L[i * (i + 1) / 2 + i];
#pragma unroll
        for (int k = 0; k < i; ++k)
            s -= L[i * (i + 1) / 2 + k] * L[i * (i + 1) / 2 + k];
        logdet += __logf(s);
        L[i * (i + 1) / 2 + i] = rsqrtf(s);
    }

    // Forward solve L y = d (y overwrites d); quad = ||y||^2
    float quad = 0.f;
#pragma unroll
    for (int i = 0; i < N_; ++i) {
        float s = d[i];
#pragma unroll
        for (int k = 0; k < i; ++k)
            s -= L[i * (i + 1) / 2 + k] * d[k];
        float y = s * L[i * (i + 1) / 2 + i];
        d[i] = y;
        quad += y * y;
    }

    float val = quad + logdet;

    // block reduction: wave64 shuffle, then LDS across 4 waves
#pragma unroll
    for (int off = 32; off > 0; off >>= 1)
        val += __shfl_down(val, off, 64);

    __shared__ float sred[4];
    const int wave = threadIdx.x >> 6;
    const int lane = threadIdx.x & 63;
    if (lane == 0) sred[wave] = val;
    __syncthreads();
    if (threadIdx.x == 0)
        partial[b] = sred[0] + sred[1] + sred[2] + sred[3];
}

__global__ __launch_bounds__(256) void gll_reduce(
    const float* __restrict__ partial,
    float* __restrict__ out)
{
    float s = 0.f;
#pragma unroll
    for (int i = 0; i < B_ / 256; ++i)
        s += partial[threadIdx.x + i * 256];

#pragma unroll
    for (int off = 32; off > 0; off >>= 1)
        s += __shfl_down(s, off, 64);

    __shared__ float sred[4];
    const int wave = threadIdx.x >> 6;
    const int lane = threadIdx.x & 63;
    if (lane == 0) sred[wave] = s;
    __syncthreads();
    if (threadIdx.x == 0) {
        float tot = sred[0] + sred[1] + sred[2] + sred[3];
        out[0] = tot / (float)((size_t)B_ * T_);
    }
}

extern "C" void kernel_launch(void* const* d_in, const int* in_sizes, int n_in,
                              void* d_out, int out_size, void* d_ws, size_t ws_size,
                              hipStream_t stream) {
    const float* pred = (const float*)d_in[0];
    const float* targ = (const float*)d_in[1];
    const float* cov  = (const float*)d_in[2];
    float* out = (float*)d_out;
    float* partial = (float*)d_ws;   // B_ floats = 4 KB

    gll_main<<<B_, 256, 0, stream>>>(pred, targ, cov, partial);
    gll_reduce<<<1, 256, 0, stream>>>(partial, out);
}